// Round 10
// baseline (303.918 us; speedup 1.0000x reference)
//
#include <hip/hip_runtime.h>
#include <hip/hip_bf16.h>

#define N_NODES 100000
#define N_EDGES 1600000
#define N_GRAPHS 512
#define NODE_DIM 64
#define GRAPH_DIM 16
#define HIDDEN 128
#define OUT_DIM 8

#define NBUCKETS 782      // ceil(N_NODES/128)
#define BNODES 128        // nodes per bucket
#define BIN_CAP 4096      // per-bucket bin capacity (avg 2046)
#define EPB 4096          // edges per binning block

__device__ __forceinline__ float bflo(unsigned u) { return __uint_as_float(u << 16); }
__device__ __forceinline__ float bfhi(unsigned u) { return __uint_as_float(u & 0xffff0000u); }

// ---------------- phase A: bin edges by dst>>7; entry = (src<<7)|(dst&127) ----------------

__global__ __launch_bounds__(256) void k_binplace(const int* __restrict__ src,
                                                  const int* __restrict__ dst,
                                                  int* __restrict__ gcur,
                                                  unsigned* __restrict__ bin) {
    __shared__ int cnt[NBUCKETS];
    __shared__ int base[NBUCKETS];
    int t = threadIdx.x;
    for (int i = t; i < NBUCKETS; i += 256) cnt[i] = 0;
    __syncthreads();
    int e0 = blockIdx.x * EPB;
#pragma unroll
    for (int k = 0; k < EPB / 256; k++) {
        int e = e0 + k * 256 + t;
        if (e < N_EDGES) atomicAdd(&cnt[dst[e] >> 7], 1);
    }
    __syncthreads();
    for (int i = t; i < NBUCKETS; i += 256) {
        int c = cnt[i];
        base[i] = (c > 0) ? atomicAdd(&gcur[i], c) : 0;
        cnt[i] = 0;
    }
    __syncthreads();
#pragma unroll
    for (int k = 0; k < EPB / 256; k++) {
        int e = e0 + k * 256 + t;
        if (e < N_EDGES) {
            int d = dst[e];
            int b = d >> 7;
            int p = atomicAdd(&cnt[b], 1);
            bin[(size_t)b * BIN_CAP + base[b] + p] = ((unsigned)src[e] << 7) | (unsigned)(d & 127);
        }
    }
}

// ---------------- phase B1: per-bucket degree count + dinv; block 0 scans gcur -> bofs ----------------

__global__ __launch_bounds__(256) void k_degscan(const int* __restrict__ gcur,
                                                 const unsigned* __restrict__ bin,
                                                 int* __restrict__ degcnt,
                                                 float* __restrict__ dinv,
                                                 int* __restrict__ bofs) {
    __shared__ int cnt[BNODES];
    int b = blockIdx.x, t = threadIdx.x;
    if (t < BNODES) cnt[t] = 0;
    __syncthreads();
    int n = gcur[b];
    const unsigned* seg = bin + (size_t)b * BIN_CAP;
    for (int i = t; i < n; i += 256) atomicAdd(&cnt[seg[i] & 127u], 1);
    __syncthreads();
    int node = b * BNODES + t;
    if (t < BNODES && node < N_NODES) {
        int c = cnt[t];
        degcnt[node] = c;
        dinv[node] = rsqrtf((float)c + 1.0f);
    }
    if (b == 0) {
        __shared__ int ls[256];
        int i0 = 4 * t;
        int c0 = (i0 + 0 < NBUCKETS) ? gcur[i0 + 0] : 0;
        int c1 = (i0 + 1 < NBUCKETS) ? gcur[i0 + 1] : 0;
        int c2 = (i0 + 2 < NBUCKETS) ? gcur[i0 + 2] : 0;
        int c3 = (i0 + 3 < NBUCKETS) ? gcur[i0 + 3] : 0;
        int s = c0 + c1 + c2 + c3;
        ls[t] = s;
        __syncthreads();
        for (int o = 1; o < 256; o <<= 1) {
            int u = (t >= o) ? ls[t - o] : 0;
            __syncthreads();
            ls[t] += u;
            __syncthreads();
        }
        int run = ls[t] - s;
        if (i0 + 0 < NBUCKETS) bofs[i0 + 0] = run; run += c0;
        if (i0 + 1 < NBUCKETS) bofs[i0 + 1] = run; run += c1;
        if (i0 + 2 < NBUCKETS) bofs[i0 + 2] = run; run += c2;
        if (i0 + 3 < NBUCKETS) bofs[i0 + 3] = run;
    }
}

// ---------------- phase B2: rowstart + CSR fill (int2 {src, w}); zeroes gt_sum ----------------

__global__ __launch_bounds__(256) void k_rowfill(const int* __restrict__ degcnt,
                                                 const int* __restrict__ bofs,
                                                 const int* __restrict__ gcur,
                                                 const unsigned* __restrict__ bin,
                                                 const float* __restrict__ dinv,
                                                 int* __restrict__ row_start,
                                                 int2* __restrict__ csre,
                                                 float* __restrict__ gt_sum) {
    __shared__ int sc[BNODES];
    __shared__ int rsl[BNODES];
    __shared__ int cnt[BNODES];
    __shared__ float dl[BNODES];
    int b = blockIdx.x, t = threadIdx.x;
    if (b < 32) gt_sum[b * 256 + t] = 0.0f;
    int node = b * BNODES + t;
    int v = 0;
    if (t < BNODES) {
        v = (node < N_NODES) ? degcnt[node] : 0;
        sc[t] = v;
    }
    __syncthreads();
    for (int o = 1; o < BNODES; o <<= 1) {
        int u = 0;
        if (t < BNODES && t >= o) u = sc[t - o];
        __syncthreads();
        if (t < BNODES) sc[t] += u;
        __syncthreads();
    }
    if (t < BNODES) {
        int rs = bofs[b] + sc[t] - v;  // exclusive
        if (node < N_NODES) row_start[node] = rs;
        rsl[t] = rs;
        cnt[t] = 0;
        dl[t] = rsqrtf((float)v + 1.0f);
    }
    __syncthreads();
    int n = gcur[b];
    const unsigned* seg = bin + (size_t)b * BIN_CAP;
    for (int i = t; i < n; i += 256) {
        unsigned e = seg[i];
        int dlidx = (int)(e & 127u);
        int s = (int)(e >> 7);
        int pos = rsl[dlidx] + atomicAdd(&cnt[dlidx], 1);
        csre[pos] = make_int2(s, __float_as_int(dinv[s] * dl[dlidx]));
    }
    if (b == NBUCKETS - 1 && t == 0) row_start[N_NODES] = N_EDGES;
}

// ---------------- fused: pack x[:, :64] to bf16 + graph feature pooling ----------------

__global__ __launch_bounds__(256) void k_packstat(const float* __restrict__ x,
                                                  const int* __restrict__ batch,
                                                  ushort* __restrict__ xb,
                                                  float* __restrict__ gt_sum) {
    int t = threadIdx.x;
    int i0 = blockIdx.x * 64;
    for (int idx = t; idx < 64 * 32; idx += 256) {
        int node = i0 + (idx >> 5);
        if (node < N_NODES) {
            int c2 = idx & 31;
            float2 v = *(const float2*)&x[(size_t)node * 80 + c2 * 2];
            __hip_bfloat16 lo = __float2bfloat16(v.x);
            __hip_bfloat16 hi = __float2bfloat16(v.y);
            ushort2 pv = make_ushort2(*(ushort*)&lo, *(ushort*)&hi);
            ((ushort2*)xb)[(size_t)node * 32 + c2] = pv;
        }
    }
    int c = t & 15, sub = t >> 4;  // 16 subs x 16 channels
    int iend = min(i0 + 64, N_NODES);
    float acc = 0.0f;
    int g = -1;
    for (int i = i0 + sub; i < iend; i += 16) {
        int bi = batch[i];
        if (bi != g) {
            if (g >= 0) atomicAdd(&gt_sum[g * GRAPH_DIM + c], acc);
            acc = 0.0f; g = bi;
        }
        acc += x[(size_t)i * 80 + NODE_DIM + c];
    }
    if (g >= 0) atomicAdd(&gt_sum[g * GRAPH_DIM + c], acc);
}

// ---- fused conv1: 4 nodes/wave guarded-unroll4 gather + full-block GEMM; zeroes gsum2 ----

#define LDX(s_) __uint_as_float((unsigned)xb[(size_t)(s_)*64 + lane] << 16)

#define G1_BLK(kX, reX, aX0, aX1)                                                  \
    if (kX + 4 <= reX) {                                                           \
        int2 e0 = csre[kX], e1 = csre[kX + 1], e2 = csre[kX + 2], e3 = csre[kX + 3]; \
        float v0 = LDX(e0.x), v1 = LDX(e1.x), v2 = LDX(e2.x), v3 = LDX(e3.x);      \
        aX0 += __int_as_float(e0.y) * v0; aX1 += __int_as_float(e1.y) * v1;        \
        aX0 += __int_as_float(e2.y) * v2; aX1 += __int_as_float(e3.y) * v3;        \
        kX += 4;                                                                   \
    } else if (kX < reX) {                                                         \
        int2 e = csre[kX];                                                         \
        aX0 += __int_as_float(e.y) * LDX(e.x);                                     \
        kX++;                                                                      \
    }

__global__ __launch_bounds__(256) void k_conv1(const int2* __restrict__ csre,
                                               const int* __restrict__ row_start,
                                               const float* __restrict__ dinv,
                                               const ushort* __restrict__ xb,
                                               const float* __restrict__ W,
                                               const float* __restrict__ bias,
                                               ushort* __restrict__ C,
                                               float* __restrict__ gsum2) {
    __shared__ float zs[16][64];
    int t = threadIdx.x;
    if (blockIdx.x < 256) gsum2[blockIdx.x * 256 + t] = 0.0f;
    int wv = t >> 6, lane = t & 63;
    int base = blockIdx.x * 16 + wv * 4;
    int rs0 = row_start[base],     rs1 = row_start[base + 1];
    int rs2 = row_start[base + 2], rs3 = row_start[base + 3];
    int rs4 = row_start[base + 4];
    int k0 = rs0, re0 = rs1, k1 = rs1, re1 = rs2;
    int k2 = rs2, re2 = rs3, k3 = rs3, re3 = rs4;
    float a00 = 0.f, a01 = 0.f, a10 = 0.f, a11 = 0.f;
    float a20 = 0.f, a21 = 0.f, a30 = 0.f, a31 = 0.f;
    while ((k0 < re0) || (k1 < re1) || (k2 < re2) || (k3 < re3)) {
        G1_BLK(k0, re0, a00, a01)
        G1_BLK(k1, re1, a10, a11)
        G1_BLK(k2, re2, a20, a21)
        G1_BLK(k3, re3, a30, a31)
    }
    float d0 = dinv[base],     d1 = dinv[base + 1];
    float d2 = dinv[base + 2], d3 = dinv[base + 3];
    zs[wv * 4 + 0][lane] = a00 + a01 + d0 * d0 * LDX(base);
    zs[wv * 4 + 1][lane] = a10 + a11 + d1 * d1 * LDX(base + 1);
    zs[wv * 4 + 2][lane] = a20 + a21 + d2 * d2 * LDX(base + 2);
    zs[wv * 4 + 3][lane] = a30 + a31 + d3 * d3 * LDX(base + 3);
    __syncthreads();
    // GEMM phase: all 256 threads; j = t&127, half hf handles rows hf*8..hf*8+7
    {
        int j = t & 127;
        int hf = t >> 7;
        float acc[8];
#pragma unroll
        for (int m = 0; m < 8; m++) acc[m] = 0.0f;
        for (int k = 0; k < 64; k++) {
            float wk = W[k * 128 + j];
#pragma unroll
            for (int m = 0; m < 8; m++) acc[m] += zs[hf * 8 + m][k] * wk;
        }
        float b = bias[j];
        size_t row0 = (size_t)blockIdx.x * 16 + hf * 8;
#pragma unroll
        for (int m = 0; m < 8; m++) {
            float v = fmaxf(acc[m] + b, 0.0f);
            __hip_bfloat16 hv = __float2bfloat16(v);
            C[(row0 + m) * 128 + j] = *(ushort*)&hv;
        }
    }
}

// ---- gather2: 4 nodes/wave guarded-unroll4 (2ch/lane) + fused mean-pool ----

#define G2_BLK(kX, reX, aX0, aX1)                                                  \
    if (kX + 4 <= reX) {                                                           \
        int2 e0 = csre[kX], e1 = csre[kX + 1], e2 = csre[kX + 2], e3 = csre[kX + 3]; \
        unsigned u0 = h[(size_t)e0.x * 64 + lane], u1 = h[(size_t)e1.x * 64 + lane]; \
        unsigned u2 = h[(size_t)e2.x * 64 + lane], u3 = h[(size_t)e3.x * 64 + lane]; \
        float w0 = __int_as_float(e0.y), w1 = __int_as_float(e1.y);                \
        float w2 = __int_as_float(e2.y), w3 = __int_as_float(e3.y);                \
        aX0.x += w0 * bflo(u0); aX0.y += w0 * bfhi(u0);                            \
        aX1.x += w1 * bflo(u1); aX1.y += w1 * bfhi(u1);                            \
        aX0.x += w2 * bflo(u2); aX0.y += w2 * bfhi(u2);                            \
        aX1.x += w3 * bflo(u3); aX1.y += w3 * bfhi(u3);                            \
        kX += 4;                                                                   \
    } else if (kX < reX) {                                                         \
        int2 e = csre[kX];                                                         \
        unsigned u = h[(size_t)e.x * 64 + lane];                                   \
        float w0 = __int_as_float(e.y);                                            \
        aX0.x += w0 * bflo(u); aX0.y += w0 * bfhi(u);                              \
        kX++;                                                                      \
    }

__global__ __launch_bounds__(256) void k_gather2(const int2* __restrict__ csre,
                                                 const int* __restrict__ row_start,
                                                 const float* __restrict__ dinv,
                                                 const unsigned* __restrict__ h,
                                                 const int* __restrict__ batch,
                                                 float* __restrict__ gsum2) {
    __shared__ float2 red[16][64];
    int t = threadIdx.x;
    int wv = t >> 6, lane = t & 63;
    int base = blockIdx.x * 16 + wv * 4;
    int rs0 = row_start[base],     rs1 = row_start[base + 1];
    int rs2 = row_start[base + 2], rs3 = row_start[base + 3];
    int rs4 = row_start[base + 4];
    int k0 = rs0, re0 = rs1, k1 = rs1, re1 = rs2;
    int k2 = rs2, re2 = rs3, k3 = rs3, re3 = rs4;
    float2 a00 = {0.f,0.f}, a01 = {0.f,0.f}, a10 = {0.f,0.f}, a11 = {0.f,0.f};
    float2 a20 = {0.f,0.f}, a21 = {0.f,0.f}, a30 = {0.f,0.f}, a31 = {0.f,0.f};
    while ((k0 < re0) || (k1 < re1) || (k2 < re2) || (k3 < re3)) {
        G2_BLK(k0, re0, a00, a01)
        G2_BLK(k1, re1, a10, a11)
        G2_BLK(k2, re2, a20, a21)
        G2_BLK(k3, re3, a30, a31)
    }
    float d0 = dinv[base],     d1 = dinv[base + 1];
    float d2 = dinv[base + 2], d3 = dinv[base + 3];
    unsigned us0 = h[(size_t)(base + 0) * 64 + lane];
    unsigned us1 = h[(size_t)(base + 1) * 64 + lane];
    unsigned us2 = h[(size_t)(base + 2) * 64 + lane];
    unsigned us3 = h[(size_t)(base + 3) * 64 + lane];
    float2 r0, r1, r2, r3;
    r0.x = a00.x + a01.x + d0 * d0 * bflo(us0);  r0.y = a00.y + a01.y + d0 * d0 * bfhi(us0);
    r1.x = a10.x + a11.x + d1 * d1 * bflo(us1);  r1.y = a10.y + a11.y + d1 * d1 * bfhi(us1);
    r2.x = a20.x + a21.x + d2 * d2 * bflo(us2);  r2.y = a20.y + a21.y + d2 * d2 * bfhi(us2);
    r3.x = a30.x + a31.x + d3 * d3 * bflo(us3);  r3.y = a30.y + a31.y + d3 * d3 * bfhi(us3);
    red[wv * 4 + 0][lane] = r0;
    red[wv * 4 + 1][lane] = r1;
    red[wv * 4 + 2][lane] = r2;
    red[wv * 4 + 3][lane] = r3;
    __syncthreads();
    int b16 = blockIdx.x * 16;
    int g0 = batch[b16];
    int gF = batch[b16 + 15];
    if (g0 == gF) {
        if (wv == 0) {
            float sx = 0.f, sy = 0.f;
#pragma unroll
            for (int q = 0; q < 16; q++) { sx += red[q][lane].x; sy += red[q][lane].y; }
            atomicAdd(&gsum2[g0 * 128 + 2 * lane], sx);
            atomicAdd(&gsum2[g0 * 128 + 2 * lane + 1], sy);
        }
    } else {
        int ga = batch[base],     gb = batch[base + 1];
        int gc = batch[base + 2], gd = batch[base + 3];
        atomicAdd(&gsum2[ga * 128 + 2 * lane], r0.x);
        atomicAdd(&gsum2[ga * 128 + 2 * lane + 1], r0.y);
        atomicAdd(&gsum2[gb * 128 + 2 * lane], r1.x);
        atomicAdd(&gsum2[gb * 128 + 2 * lane + 1], r1.y);
        atomicAdd(&gsum2[gc * 128 + 2 * lane], r2.x);
        atomicAdd(&gsum2[gc * 128 + 2 * lane + 1], r2.y);
        atomicAdd(&gsum2[gd * 128 + 2 * lane], r3.x);
        atomicAdd(&gsum2[gd * 128 + 2 * lane + 1], r3.y);
    }
}

// ---------------- final: gcnt (binary search) + z = mean2 @ W2 + b2 ; MLP ----------------

__global__ __launch_bounds__(128) void k_mlp(const float* __restrict__ gsum2,
                                             const float* __restrict__ gt_sum,
                                             const int* __restrict__ batch,
                                             const float* __restrict__ W2,
                                             const float* __restrict__ b2,
                                             const float* __restrict__ Wm1,
                                             const float* __restrict__ bm1,
                                             const float* __restrict__ Wm2,
                                             const float* __restrict__ bm2,
                                             float* __restrict__ out) {
    __shared__ float srow[HIDDEN];
    __shared__ float g144[HIDDEN + GRAPH_DIM];
    __shared__ float sm[HIDDEN];
    __shared__ int cnt_sh;
    int b = blockIdx.x;
    int j = threadIdx.x;  // 0..127
    float raw = gsum2[b * 128 + j];
    float gtraw = (j < GRAPH_DIM) ? gt_sum[b * GRAPH_DIM + j] : 0.0f;
    if (j == 0) {
        int lo = 0, hi = N_NODES;
        while (lo < hi) { int m = (lo + hi) >> 1; if (batch[m] < b) lo = m + 1; else hi = m; }
        int a = lo;
        lo = 0; hi = N_NODES;
        while (lo < hi) { int m = (lo + hi) >> 1; if (batch[m] < b + 1) lo = m + 1; else hi = m; }
        cnt_sh = lo - a;
    }
    __syncthreads();
    float inv = 1.0f / fmaxf((float)cnt_sh, 1.0f);
    srow[j] = raw * inv;
    if (j < GRAPH_DIM) g144[128 + j] = gtraw * inv;
    __syncthreads();
    float z = b2[j];
    for (int k = 0; k < 128; k++) z += srow[k] * W2[k * 128 + j];
    g144[j] = z;
    __syncthreads();
    float acc = bm1[j];
    for (int k = 0; k < HIDDEN + GRAPH_DIM; k++) acc += g144[k] * Wm1[k * 128 + j];
    sm[j] = fmaxf(acc, 0.0f);
    __syncthreads();
    if (j < OUT_DIM) {
        float o = bm2[j];
        for (int k = 0; k < 128; k++) o += sm[k] * Wm2[k * OUT_DIM + j];
        out[b * OUT_DIM + j] = o;
    }
}

extern "C" void kernel_launch(void* const* d_in, const int* in_sizes, int n_in,
                              void* d_out, int out_size, void* d_ws, size_t ws_size,
                              hipStream_t stream) {
    const float* x    = (const float*)d_in[0];
    const int*   edge = (const int*)d_in[1];
    const int*   src  = edge;
    const int*   dst  = edge + N_EDGES;
    const int*   batch= (const int*)d_in[2];
    const float* W1   = (const float*)d_in[3];
    const float* b1   = (const float*)d_in[4];
    const float* W2   = (const float*)d_in[5];
    const float* b2   = (const float*)d_in[6];
    const float* Wm1  = (const float*)d_in[7];
    const float* bm1  = (const float*)d_in[8];
    const float* Wm2  = (const float*)d_in[9];
    const float* bm2  = (const float*)d_in[10];
    float* out = (float*)d_out;

    // workspace layout (~66 MB)
    char* ws = (char*)d_ws;
    char* p = ws;
    unsigned* bin   = (unsigned*)p;  p += (size_t)NBUCKETS * BIN_CAP * 4;   // 12.8 MB
    int2*  csre     = (int2*)p;      p += ((size_t)N_EDGES + 8) * 8;        // 12.8 MB (+pad)
    ushort* h1b     = (ushort*)p;    p += (size_t)N_NODES * 128 * 2;        // h1 bf16 25.6 MB
    ushort* xb      = (ushort*)p;    p += (size_t)N_NODES * 64 * 2;         // x bf16 12.8 MB
    int*   degcnt   = (int*)p;       p += (size_t)NBUCKETS * BNODES * 4;
    int*   row_start= (int*)p;       p += ((size_t)N_NODES + 1) * 4;
    float* dinv     = (float*)p;     p += (size_t)N_NODES * 4;
    int*   gcur     = (int*)p;       p += (size_t)NBUCKETS * 4;
    int*   bofs     = (int*)p;       p += (size_t)NBUCKETS * 4;
    float* gt_sum   = (float*)p;     p += (size_t)N_GRAPHS * GRAPH_DIM * 4;
    float* gsum2    = (float*)p;     p += (size_t)N_GRAPHS * 128 * 4;

    hipMemsetAsync(gcur, 0, (size_t)NBUCKETS * 4, stream);

    // CSR build
    k_binplace<<<(N_EDGES + EPB - 1) / EPB, 256, 0, stream>>>(src, dst, gcur, bin);
    k_degscan<<<NBUCKETS, 256, 0, stream>>>(gcur, bin, degcnt, dinv, bofs);
    k_rowfill<<<NBUCKETS, 256, 0, stream>>>(degcnt, bofs, gcur, bin, dinv, row_start, csre, gt_sum);

    // bf16 pack + graph stats
    k_packstat<<<(N_NODES + 63) / 64, 256, 0, stream>>>(x, batch, xb, gt_sum);

    // conv1 fused: z1 = A_hat * x64 (LDS) ; h1 = relu(z1 @ W1 + b1) (bf16)
    k_conv1<<<N_NODES / 16, 256, 0, stream>>>(csre, row_start, dinv, xb, W1, b1, h1b, gsum2);

    // conv2 pooled: gsum2[g] = sum_{node in g} (A_hat h1)[node]
    k_gather2<<<N_NODES / 16, 256, 0, stream>>>(csre, row_start, dinv,
                                                (const unsigned*)h1b, batch, gsum2);

    // final: gcnt + z = (gsum2/cnt) @ W2 + b2 ; MLP
    k_mlp<<<N_GRAPHS, 128, 0, stream>>>(gsum2, gt_sum, batch, W2, b2, Wm1, bm1, Wm2, bm2, out);
}